// Round 13
// baseline (2001.024 us; speedup 1.0000x reference)
//
#include <hip/hip_runtime.h>

// Decoder_8014408974552 R17: barrier-free -- B-frags global->register.
// R16 POST-MORTEM: arch-VGPR ceiling is 256 (v0..v255); MFMA A/B operands
// must be arch regs. R16's 320-reg double-buffer forced accvgpr shuffling ->
// regression. R17 removes the REASON for the phase machine instead: the
// 24KB/phase LDS staging + 1500 barriers exist only to share weights among
// 4 waves, but the 1.23MB stream is L2-resident by construction. So: load
// B-frags straight from global into a 12-frag double-buffer (bfA/bfB = 96
// arch regs; hold 96 + xf 32 + bf 96 ~ 250 <= 256). Consume bfA (12 MFMA
// ~384cyc) | load next half -> bfA | consume bfB | load -> bfB: ~384cyc
// lookahead >= L2 latency. hn is wave-private -> waves share NOTHING ->
// zero __syncthreads; one raw s_barrier per t bounds drift so the 4 waves
// stay on the same 24KB L1 window. Frag values + accumulation order are
// bit-identical to R15 (absmax 0.125). prep/stream layout unchanged.

#define TT  30
#define PHU 12288   // u16 per phase (24576 B) -- prep layout unit
#define HPU 6144    // u16 per half-phase (12288 B); 100 halves per t
#define HS  392     // hn row stride in u16 (784 B; cols 384..391 = sst)

typedef unsigned short u16;
typedef __bf16 bf16x8 __attribute__((ext_vector_type(8)));
typedef u16    u16x8  __attribute__((ext_vector_type(8)));
typedef float  f32x16 __attribute__((ext_vector_type(16)));

__device__ __forceinline__ u16 f2b(float f){           // fp32 -> bf16 RNE
  unsigned u = __float_as_uint(f);
  u += 0x7FFFu + ((u >> 16) & 1u);
  return (u16)(u >> 16);
}
__device__ __forceinline__ float b2f(u16 h){ return __uint_as_float(((unsigned)h) << 16); }

__device__ __forceinline__ f32x16 mfma32(u16x8 a, u16x8 b, f32x16 c){
  return __builtin_amdgcn_mfma_f32_32x32x16_bf16(
      __builtin_bit_cast(bf16x8, a), __builtin_bit_cast(bf16x8, b), c, 0, 0, 0);
}
__device__ __forceinline__ void lds_fence(){
  asm volatile("s_waitcnt lgkmcnt(0)" ::: "memory");
  __builtin_amdgcn_sched_barrier(0);
}
__device__ __forceinline__ float sigf(float x){ return __builtin_amdgcn_rcpf(1.f + __expf(-x)); }
__device__ __forceinline__ float tanh_(float x){ return 2.f*__builtin_amdgcn_rcpf(1.f + __expf(-2.f*x)) - 1.f; }

// ---------------------------------------------------------------- prep ----
// EXACT R4/R11/R15 layout (50 phases x 24 frags x 1024 B per step):
//   c*4+0 : gi  [gi_r kf0..7][gi_z kf0..7][gi_n kf0..7]   (K=128)
//   c*4+1 : gh_r kf0..23   c*4+2 : gh_z   c*4+3 : gh_n     (K=384)
//   48,49 : Wd1 col-tile 0,1  kf0..23
// frag: u16 idx (lane&31 + 32*(lane>>5))*8 + j -> B[k][n], n=c*32+(lane&31),
// k = kf*16 + (lane>>5)*8 + j.  Half h = 2p + f/12 at h*HPU; frag f%12.
__global__ void prep_kernel(const float* __restrict__ Wih, const float* __restrict__ Whh,
                            const float* __restrict__ Wd1, const float* __restrict__ Wd2,
                            const float* __restrict__ bih, const float* __restrict__ bhh,
                            const float* __restrict__ Ws,  const float* __restrict__ bs,
                            const float* __restrict__ Wp,  const float* __restrict__ bp,
                            u16* __restrict__ stream, u16* __restrict__ wd2p,
                            u16* __restrict__ wxp, float* __restrict__ gb)
{
  int i = blockIdx.x*blockDim.x + threadIdx.x;
  if (i < 442368){  // W_hh [1152][384]
    int row = i/384, k = i - row*384;
    int g = row/384, unit = row - g*384, c = unit>>5, lc = unit&31;
    int kf = k>>4, hl = (k>>3)&1, j = k&7;
    int phase = c*4 + 1 + g;
    stream[(size_t)phase*PHU + kf*512 + (lc+32*hl)*8 + j] = f2b(Whh[i]);
  }
  if (i < 147456){  // W_ih [1152][128]
    int row = i>>7, k = i&127;
    int g = row/384, unit = row - g*384, c = unit>>5, lc = unit&31;
    int kf = k>>4, hl = (k>>3)&1, j = k&7;
    int phase = c*4;
    stream[(size_t)phase*PHU + (g*8+kf)*512 + (lc+32*hl)*8 + j] = f2b(Wih[i]);
  }
  if (i < 24576){   // Wd1 [64][384]
    int row = i/384, k = i - row*384;
    int ct = row>>5, lc = row&31;
    int kf = k>>4, hl = (k>>3)&1, j = k&7;
    int phase = 48 + ct;
    stream[(size_t)phase*PHU + kf*512 + (lc+32*hl)*8 + j] = f2b(Wd1[i]);
  }
  if (i < 2048){    // Wd2 padded B-frags [4 kf][512] (n>=3 -> 0)
    int kf = i>>9, r = i&511;
    int n = (r>>3)&31, hl = r>>8, j = r&7;
    int k = kf*16 + hl*8 + j;
    wd2p[i] = f2b((n<3) ? Wd2[n*64 + k] : 0.f);
  }
  if (i < 2048){    // x-MLP B-frags [4 tiles][512]: K=16 (k=0..7 feat, 8..15 zero)
    int tl = i>>9, r = i&511;
    int n = (r>>3)&31, hl = r>>8, j = r&7;
    int k = hl*8 + j, u = tl*32 + n;
    float v = 0.f;
    if      (k <= 2) v = Ws[u*3 + k];
    else if (k == 3) v = bs[u];
    else if (k <= 6) v = Wp[u*3 + (k-4)];
    else if (k == 7) v = bp[u];
    wxp[i] = f2b(v);
  }
  if (i < 384){     // fused gate biases per hidden unit: {r, z, n_i, n_h}
    gb[i*4+0] = bih[i]       + bhh[i];
    gb[i*4+1] = bih[384+i]   + bhh[384+i];
    gb[i*4+2] = bih[768+i];
    gb[i*4+3] = bhh[768+i];
  }
}

// load half 'nh' (12 frags, 16B/lane coalesced, L2-hot) into register buffer
#define LOAD_HALF(BN) { \
  const u16* s_ = stream + (size_t)nh*HPU + lane*8; \
  _Pragma("unroll") for (int f_=0; f_<12; ++f_) BN[f_] = *(const u16x8*)(s_ + f_*512); \
  nh = (nh==99) ? 0 : nh+1; }

// gi phase: frag q: 0-7 aR/xf[q], 8-15 aZ/xf[q-8], 16-23 aNI/xf[q-16]
#define PH_GI() { \
  _Pragma("unroll") for (int q_=0;q_<8;++q_) aR  = mfma32(xf[q_],   bfA[q_],   aR); \
  _Pragma("unroll") for (int q_=0;q_<4;++q_) aZ  = mfma32(xf[q_],   bfA[8+q_], aZ); \
  LOAD_HALF(bfA); \
  _Pragma("unroll") for (int q_=0;q_<4;++q_) aZ  = mfma32(xf[4+q_], bfB[q_],   aZ); \
  _Pragma("unroll") for (int q_=0;q_<8;++q_) aNI = mfma32(xf[q_],   bfB[4+q_], aNI); \
  LOAD_HALF(bfB); }

// gh-type phase: 24-chain on ACC (hold[0..11] from bfA, hold[12..23] from bfB)
#define PH_GH(ACC) { \
  _Pragma("unroll") for (int k_=0;k_<12;++k_) ACC = mfma32(hold[k_],    bfA[k_], ACC); \
  LOAD_HALF(bfA); \
  _Pragma("unroll") for (int k_=0;k_<12;++k_) ACC = mfma32(hold[12+k_], bfB[k_], ACC); \
  LOAD_HALF(bfB); }

// ---------------------------------------------------------------- main ----
__global__ __launch_bounds__(256, 1)
void gru_main(const float* __restrict__ ih, const float* __restrict__ plan,
              const float* __restrict__ gate, const float* __restrict__ istate,
              const u16* __restrict__ stream, const u16* __restrict__ wd2p,
              const u16* __restrict__ wxp, const float* __restrict__ gb,
              const float* __restrict__ bd1, const float* __restrict__ bd2,
              float* __restrict__ out)
{
  __shared__ __attribute__((aligned(16))) u16 hn[4][32*HS]; // 100352 B (wave-private h + sst pad)
  // no weight-staging LDS, no cross-wave sharing -> no __syncthreads anywhere

  const int tid  = threadIdx.x;
  const int wave = tid >> 6, lane = tid & 63;
  const int m    = lane & 31, hl = lane >> 5;
  const int R0   = blockIdx.x*128 + wave*32;   // wave's 32 batch rows
  u16* hw = hn[wave];

  const float gt    = gate[R0 + m];
  const float bd1v0 = bd1[m], bd1v1 = bd1[32+m];
  const float bd2v  = (m<3) ? bd2[m] : 0.f;

  if (lane < 32){   // sst lives in hn row padding (cols 384..391 = 4 f32)
    const float* sp = istate + (size_t)(R0+lane)*3;
    float* q = (float*)&hw[lane*HS + 384];
    q[0]=sp[0]; q[1]=sp[1]; q[2]=sp[2]; q[3]=0.f;
  }

  // initial hidden -> A-frags AND the persistent LDS h-buffer
  u16x8 hold[24];
#pragma unroll
  for (int kf=0; kf<24; ++kf){
    const float* p = ih + (size_t)(R0+m)*384 + kf*16 + hl*8;
    float4 a = *(const float4*)p;
    float4 b = *(const float4*)(p+4);
    u16x8 v;
    v[0]=f2b(a.x); v[1]=f2b(a.y); v[2]=f2b(a.z); v[3]=f2b(a.w);
    v[4]=f2b(b.x); v[5]=f2b(b.y); v[6]=f2b(b.z); v[7]=f2b(b.w);
    hold[kf]=v;
    *(u16x8*)&hw[m*HS + kf*16 + hl*8] = v;
  }

  // register double-buffer pipeline: bfA=half 2p, bfB=half 2p+1 at phase p
  u16x8 bfA[12], bfB[12];
  int nh = 0;
  LOAD_HALF(bfA);     // half 0
  LOAD_HALF(bfB);     // half 1; nh=2

#pragma unroll 1
  for (int t=0; t<TT; ++t){
    // raw barrier (no memory drain): bound inter-wave drift for L1 locality
    __builtin_amdgcn_s_barrier();

    // ---- x = (state@Ws^T+bs) + gate*(plan@Wp^T+bp) via one padded-K MFMA per tile
    u16x8 a8;
    {
      float4 sv = *(const float4*)&hw[m*HS + 384];   // sst in hn padding
      const float* pp = plan + (size_t)(R0+m)*(TT*3) + t*3;
      float f0=sv.x, f1=sv.y, f2=sv.z, f3=1.f;
      float f4=gt*pp[0], f5=gt*pp[1], f6=gt*pp[2], f7=gt;
      if (hl){ a8[0]=0;a8[1]=0;a8[2]=0;a8[3]=0;a8[4]=0;a8[5]=0;a8[6]=0;a8[7]=0; }
      else { a8[0]=f2b(f0);a8[1]=f2b(f1);a8[2]=f2b(f2);a8[3]=f2b(f3);
             a8[4]=f2b(f4);a8[5]=f2b(f5);a8[6]=f2b(f6);a8[7]=f2b(f7); }
    }
    u16x8 xf[8];
#pragma unroll
    for (int tl=0; tl<4; ++tl){
      f32x16 ax;
#pragma unroll
      for (int r=0;r<16;++r) ax[r]=0.f;
      ax = mfma32(a8, *(const u16x8*)(wxp + tl*512 + lane*8), ax);
      // C-layout -> hn chunk-0 slice (scratch) -> A-frags (wave-private)
#pragma unroll
      for (int r=0;r<16;++r){
        int row = (r&3) + ((r>>2)<<3) + 4*hl;
        hw[row*HS + m] = f2b(ax[r]);
      }
      lds_fence();
      xf[2*tl]   = *(const u16x8*)&hw[m*HS + hl*8];
      xf[2*tl+1] = *(const u16x8*)&hw[m*HS + 16 + hl*8];
      lds_fence();
    }
    // restore chunk-0 slice of old h from hold (CONSTANT indices)
    *(u16x8*)&hw[m*HS + hl*8]      = hold[0];
    *(u16x8*)&hw[m*HS + 16 + hl*8] = hold[1];
    lds_fence();

#pragma unroll 1
    for (int c=0; c<12; ++c){
      f32x16 aR, aZ, aNI, aNH;
      {
        const float4 b4 = *(const float4*)(gb + (size_t)(c*32+m)*4);
#pragma unroll
        for (int r=0;r<16;++r){ aR[r]=b4.x; aZ[r]=b4.y; aNI[r]=b4.z; aNH[r]=b4.w; }
      }
      PH_GI();        // phase c*4+0: gi
      PH_GH(aR);      // phase c*4+1: gh_r
      PH_GH(aZ);      // phase c*4+2: gh_z
      PH_GH(aNH);     // phase c*4+3: gh_n
      // GRU elementwise blend, in place (wave-private hn slice)
#pragma unroll
      for (int r=0;r<16;++r){
        int row = (r&3) + ((r>>2)<<3) + 4*hl;
        float rr = sigf(aR[r]);
        float zz = sigf(aZ[r]);
        float nn = tanh_(aNI[r] + rr*aNH[r]);
        int off = row*HS + c*32 + m;
        float ho = b2f(hw[off]);             // old h
        hw[off] = f2b((1.f-zz)*nn + zz*ho);  // new h, in place
      }
    } // chunks

    // ---- reload hold[] from hn (own blends; compiler orders lgkm)
    lds_fence();
#pragma unroll
    for (int kf=0; kf<24; ++kf)
      hold[kf] = *(const u16x8*)&hw[m*HS + kf*16 + hl*8];

    // ---- decode: d1 = elu(h@Wd1^T + bd1) [2 tiles], then d2 via padded-N MFMA
    f32x16 a0, a1;
#pragma unroll
    for (int r=0;r<16;++r){ a0[r]=bd1v0; a1[r]=bd1v1; }
    PH_GH(a0);        // phase 48: Wd1 tile 0
    PH_GH(a1);        // phase 49: Wd1 tile 1 (final loads wrap to half 0,1)
    {
      // Wd2 frags (short live range, L1-hot)
      u16x8 wd2f0 = *(const u16x8*)(wd2p + 0*512 + lane*8);
      u16x8 wd2f1 = *(const u16x8*)(wd2p + 1*512 + lane*8);
      u16x8 wd2f2 = *(const u16x8*)(wd2p + 2*512 + lane*8);
      u16x8 wd2f3 = *(const u16x8*)(wd2p + 3*512 + lane*8);

      f32x16 ao;
#pragma unroll
      for (int r=0;r<16;++r) ao[r]=0.f;
      // pass 0: d1 units 0..31 (hn chunk-0 slice as scratch)
#pragma unroll
      for (int r=0;r<16;++r){
        int row = (r&3) + ((r>>2)<<3) + 4*hl;
        float e = a0[r]; e = e>0.f ? e : (__expf(e)-1.f);
        hw[row*HS + m] = f2b(e);
      }
      lds_fence();
      {
        u16x8 af0 = *(const u16x8*)&hw[m*HS + hl*8];
        u16x8 af1 = *(const u16x8*)&hw[m*HS + 16 + hl*8];
        ao = mfma32(af0, wd2f0, ao);
        ao = mfma32(af1, wd2f1, ao);
      }
      lds_fence();
      // pass 1: d1 units 32..63
#pragma unroll
      for (int r=0;r<16;++r){
        int row = (r&3) + ((r>>2)<<3) + 4*hl;
        float e = a1[r]; e = e>0.f ? e : (__expf(e)-1.f);
        hw[row*HS + m] = f2b(e);
      }
      lds_fence();
      {
        u16x8 af0 = *(const u16x8*)&hw[m*HS + hl*8];
        u16x8 af1 = *(const u16x8*)&hw[m*HS + 16 + hl*8];
        ao = mfma32(af0, wd2f2, ao);
        ao = mfma32(af1, wd2f3, ao);
      }
      lds_fence();
      // restore chunk-0 slice of NEW h from hold (CONSTANT indices)
      *(u16x8*)&hw[m*HS + hl*8]      = hold[0];
      *(u16x8*)&hw[m*HS + 16 + hl*8] = hold[1];

      // out + state update (C cols 0..2 valid); sst in hn padding
#pragma unroll
      for (int r=0;r<16;++r){
        int row = (r&3) + ((r>>2)<<3) + 4*hl;
        if (m < 3){
          float* q = (float*)&hw[row*HS + 384];
          float ns = q[m] + ao[r] + bd2v;
          out[(size_t)(R0+row)*(TT*3) + t*3 + m] = ns;
          q[m] = ns;
        }
      }
    }
  } // t
}

// -------------------------------------------------------------- launch ----
extern "C" void kernel_launch(void* const* d_in, const int* in_sizes, int n_in,
                              void* d_out, int out_size, void* d_ws, size_t ws_size,
                              hipStream_t stream)
{
  (void)in_sizes; (void)n_in; (void)out_size; (void)ws_size;
  const float* ih     = (const float*)d_in[0];
  const float* plan   = (const float*)d_in[1];
  const float* gatep  = (const float*)d_in[2];
  const float* istate = (const float*)d_in[3];
  const float* Wp     = (const float*)d_in[4];
  const float* bp     = (const float*)d_in[5];
  const float* Ws     = (const float*)d_in[6];
  const float* bs     = (const float*)d_in[7];
  const float* Wih    = (const float*)d_in[8];
  const float* bih    = (const float*)d_in[9];
  const float* Whh    = (const float*)d_in[10];
  const float* bhh    = (const float*)d_in[11];
  const float* Wd1    = (const float*)d_in[12];
  const float* bd1    = (const float*)d_in[13];
  const float* Wd2    = (const float*)d_in[14];
  const float* bd2    = (const float*)d_in[15];

  // workspace layout (~1.25 MB)
  u16*   wstream = (u16*)d_ws;                         // 614400 u16 = 1228800 B
  u16*   wd2p    = (u16*)((char*)d_ws + 1228800);      //   2048 u16 =    4096 B
  u16*   wxp     = (u16*)((char*)d_ws + 1232896);      //   2048 u16 =    4096 B
  float* gb      = (float*)((char*)d_ws + 1236992);    //   1536 f32 =    6144 B

  prep_kernel<<<1728, 256, 0, stream>>>(Wih, Whh, Wd1, Wd2, bih, bhh, Ws, bs, Wp, bp,
                                        wstream, wd2p, wxp, gb);
  gru_main<<<256, 256, 0, stream>>>(ih, plan, gatep, istate,
                                    wstream, wd2p, wxp, gb, bd1, bd2, (float*)d_out);
}

// Round 14
// 1523.546 us; speedup vs baseline: 1.3134x; 1.3134x over previous
//
#include <hip/hip_runtime.h>

// Decoder_8014408974552 R18: R15 + half-granularity cross-phase ping-pong.
// R17 POST-MORTEM: global->reg B-frags are L1-feed-bound (24KB/wave/phase
// through ~64B/cyc vector path = 1536cyc/CU > LDS's shared 128B/cyc) ->
// regressed; 4-wave shared-LDS staging is L2-optimal. R15's residual is the
// POST-BARRIER COLD START: 96 ds_reads burst each phase (~1150cyc drain)
// while MFMAs wait. R16 fixed that but held 288 live arch regs (>256 cap).
// R18 fits: bfA[12]/bfB[12] only (96 regs). Phase p enters with bfA = half
// 2p IN REGISTERS (loaded during p-1) -> MFMAs fire at barrier-exit;
// bfB <- half 2p+1 early (384cyc slack); after MFMA11, bfA <- half 2p+2
// (cross-barrier lookahead); MFMA12-23 from bfB. Staging 1.5-ahead
// (halves 2p+4,2p+5). Invariants verified: vmcnt(3) at end-of-p => halves
// <=2p+4 landed; staged slots (2p+4)%5,(2p)%5 are exactly those drained by
// p-1's lgkmcnt(0)+barrier; read slots (2p+1)%5,(2p+2)%5 disjoint from
// staged; prologue isolates slot-0 reuse with a one-time extra barrier;
// 100 halves/t == 0 mod 5 -> seamless t-wrap. Arch regs ~245 <= 256.
// Frag values + accumulation order identical -> absmax 0.125.

#define TT  30
#define NPH 50
#define PHU 12288   // u16 per phase (24576 B) -- prep layout unit
#define HPU 6144    // u16 per half-phase slot (12288 B)
#define STRU 614400 // u16 in the whole stream (100 halves)
#define HS  392     // hn row stride in u16 (784 B; cols 384..391 = sst)

typedef unsigned short u16;
typedef __bf16 bf16x8 __attribute__((ext_vector_type(8)));
typedef u16    u16x8  __attribute__((ext_vector_type(8)));
typedef float  f32x16 __attribute__((ext_vector_type(16)));

__device__ __forceinline__ u16 f2b(float f){           // fp32 -> bf16 RNE
  unsigned u = __float_as_uint(f);
  u += 0x7FFFu + ((u >> 16) & 1u);
  return (u16)(u >> 16);
}
__device__ __forceinline__ float b2f(u16 h){ return __uint_as_float(((unsigned)h) << 16); }

__device__ __forceinline__ f32x16 mfma32(u16x8 a, u16x8 b, f32x16 c){
  return __builtin_amdgcn_mfma_f32_32x32x16_bf16(
      __builtin_bit_cast(bf16x8, a), __builtin_bit_cast(bf16x8, b), c, 0, 0, 0);
}
__device__ __forceinline__ void lds_fence(){
  asm volatile("s_waitcnt lgkmcnt(0)" ::: "memory");
  __builtin_amdgcn_sched_barrier(0);
}
__device__ __forceinline__ float sigf(float x){ return __builtin_amdgcn_rcpf(1.f + __expf(-x)); }
__device__ __forceinline__ float tanh_(float x){ return 2.f*__builtin_amdgcn_rcpf(1.f + __expf(-2.f*x)) - 1.f; }

__device__ __forceinline__ void stage16(const u16* g, u16* l){
  __builtin_amdgcn_global_load_lds(
      (const __attribute__((address_space(1))) unsigned int*)g,
      (__attribute__((address_space(3))) unsigned int*)l, 16, 0, 0);
}

// ---------------------------------------------------------------- prep ----
// EXACT R4/R11/R15 layout (50 phases x 24 frags x 1024 B per step):
//   c*4+0 : gi  [gi_r kf0..7][gi_z kf0..7][gi_n kf0..7]   (K=128)
//   c*4+1 : gh_r kf0..23   c*4+2 : gh_z   c*4+3 : gh_n     (K=384)
//   48,49 : Wd1 col-tile 0,1  kf0..23
// frag: u16 idx (lane&31 + 32*(lane>>5))*8 + j -> B[k][n], n=c*32+(lane&31),
// k = kf*16 + (lane>>5)*8 + j.  Half h = 2p + f/12 at h*HPU; frag f%12.
__global__ void prep_kernel(const float* __restrict__ Wih, const float* __restrict__ Whh,
                            const float* __restrict__ Wd1, const float* __restrict__ Wd2,
                            const float* __restrict__ bih, const float* __restrict__ bhh,
                            const float* __restrict__ Ws,  const float* __restrict__ bs,
                            const float* __restrict__ Wp,  const float* __restrict__ bp,
                            u16* __restrict__ stream, u16* __restrict__ wd2p,
                            u16* __restrict__ wxp, float* __restrict__ gb)
{
  int i = blockIdx.x*blockDim.x + threadIdx.x;
  if (i < 442368){  // W_hh [1152][384]
    int row = i/384, k = i - row*384;
    int g = row/384, unit = row - g*384, c = unit>>5, lc = unit&31;
    int kf = k>>4, hl = (k>>3)&1, j = k&7;
    int phase = c*4 + 1 + g;
    stream[(size_t)phase*PHU + kf*512 + (lc+32*hl)*8 + j] = f2b(Whh[i]);
  }
  if (i < 147456){  // W_ih [1152][128]
    int row = i>>7, k = i&127;
    int g = row/384, unit = row - g*384, c = unit>>5, lc = unit&31;
    int kf = k>>4, hl = (k>>3)&1, j = k&7;
    int phase = c*4;
    stream[(size_t)phase*PHU + (g*8+kf)*512 + (lc+32*hl)*8 + j] = f2b(Wih[i]);
  }
  if (i < 24576){   // Wd1 [64][384]
    int row = i/384, k = i - row*384;
    int ct = row>>5, lc = row&31;
    int kf = k>>4, hl = (k>>3)&1, j = k&7;
    int phase = 48 + ct;
    stream[(size_t)phase*PHU + kf*512 + (lc+32*hl)*8 + j] = f2b(Wd1[i]);
  }
  if (i < 2048){    // Wd2 padded B-frags [4 kf][512] (n>=3 -> 0)
    int kf = i>>9, r = i&511;
    int n = (r>>3)&31, hl = r>>8, j = r&7;
    int k = kf*16 + hl*8 + j;
    wd2p[i] = f2b((n<3) ? Wd2[n*64 + k] : 0.f);
  }
  if (i < 2048){    // x-MLP B-frags [4 tiles][512]: K=16 (k=0..7 feat, 8..15 zero)
    int tl = i>>9, r = i&511;
    int n = (r>>3)&31, hl = r>>8, j = r&7;
    int k = hl*8 + j, u = tl*32 + n;
    float v = 0.f;
    if      (k <= 2) v = Ws[u*3 + k];
    else if (k == 3) v = bs[u];
    else if (k <= 6) v = Wp[u*3 + (k-4)];
    else if (k == 7) v = bp[u];
    wxp[i] = f2b(v);
  }
  if (i < 384){     // fused gate biases per hidden unit: {r, z, n_i, n_h}
    gb[i*4+0] = bih[i]       + bhh[i];
    gb[i*4+1] = bih[384+i]   + bhh[384+i];
    gb[i*4+2] = bih[768+i];
    gb[i*4+3] = bhh[768+i];
  }
}

// load 12 frags from slot S into register half-buffer BN
#define LOADHALF(BN, S) { \
  const u16* W_ = wb + (S)*HPU + lane*8; \
  _Pragma("unroll") for (int f_=0; f_<12; ++f_) BN[f_] = *(const u16x8*)(W_ + f_*512); }

// gh-type phase: MFMA0-11 from bfA(half 2p, preloaded) while bfB<-half 2p+1;
// then bfA<-half 2p+2 (cross-barrier lookahead) + stage; MFMA12-23 from bfB.
#define PH_GH(ACC) { \
  LOADHALF(bfB, s1); \
  _Pragma("unroll") for (int k_=0;k_<12;++k_) ACC = mfma32(hold[k_], bfA[k_], ACC); \
  LOADHALF(bfA, s2); \
  stage_half(); stage_half(); \
  _Pragma("unroll") for (int k_=0;k_<12;++k_) ACC = mfma32(hold[12+k_], bfB[k_], ACC); \
  phase_end(); }

// gi-type phase: frag f: 0-7 aR/xf[f], 8-15 aZ/xf[f-8], 16-23 aNI/xf[f-16]
#define PH_GI() { \
  LOADHALF(bfB, s1); \
  _Pragma("unroll") for (int q_=0;q_<8;++q_) aR = mfma32(xf[q_], bfA[q_],   aR); \
  _Pragma("unroll") for (int q_=0;q_<4;++q_) aZ = mfma32(xf[q_], bfA[8+q_], aZ); \
  LOADHALF(bfA, s2); \
  stage_half(); stage_half(); \
  _Pragma("unroll") for (int q_=0;q_<4;++q_) aZ  = mfma32(xf[4+q_], bfB[q_],   aZ); \
  _Pragma("unroll") for (int q_=0;q_<8;++q_) aNI = mfma32(xf[q_],   bfB[4+q_], aNI); \
  phase_end(); }

// ---------------------------------------------------------------- main ----
__global__ __launch_bounds__(256, 1)
void gru_main(const float* __restrict__ ih, const float* __restrict__ plan,
              const float* __restrict__ gate, const float* __restrict__ istate,
              const u16* __restrict__ stream, const u16* __restrict__ wd2p,
              const u16* __restrict__ wxp, const float* __restrict__ gb,
              const float* __restrict__ bd1, const float* __restrict__ bd2,
              float* __restrict__ out)
{
  __shared__ __attribute__((aligned(16))) u16 wb[5*HPU];    //  61440 B, 5 half-slots
  __shared__ __attribute__((aligned(16))) u16 hn[4][32*HS]; // 100352 B (h + sst pad)
  // total 161792 B <= 163840 -> 1 block/CU (LDS-bound), 1 wave/SIMD, arch-VGPR cap 256

  const int tid  = threadIdx.x;
  const int wave = tid >> 6, lane = tid & 63;
  const int m    = lane & 31, hl = lane >> 5;
  const int R0   = blockIdx.x*128 + wave*32;   // wave's 32 batch rows
  u16* hw = hn[wave];

  const float gt    = gate[R0 + m];
  const float bd1v0 = bd1[m], bd1v1 = bd1[32+m];
  const float bd2v  = (m<3) ? bd2[m] : 0.f;

  if (lane < 32){   // sst lives in hn row padding (cols 384..391 = 4 f32)
    const float* sp = istate + (size_t)(R0+lane)*3;
    float* q = (float*)&hw[lane*HS + 384];
    q[0]=sp[0]; q[1]=sp[1]; q[2]=sp[2]; q[3]=0.f;
  }

  // initial hidden -> A-frags AND the persistent LDS h-buffer
  u16x8 hold[24];
#pragma unroll
  for (int kf=0; kf<24; ++kf){
    const float* p = ih + (size_t)(R0+m)*384 + kf*16 + hl*8;
    float4 a = *(const float4*)p;
    float4 b = *(const float4*)(p+4);
    u16x8 v;
    v[0]=f2b(a.x); v[1]=f2b(a.y); v[2]=f2b(a.z); v[3]=f2b(a.w);
    v[4]=f2b(b.x); v[5]=f2b(b.y); v[6]=f2b(b.z); v[7]=f2b(b.w);
    hold[kf]=v;
    *(u16x8*)&hw[m*HS + kf*16 + hl*8] = v;
  }

  // ---- staging pipeline state (1.5-ahead): phase p stages halves 2p+4,2p+5;
  //      bfB <- slot s1 = (2p+1)%5; bfA(next) <- slot s2 = (2p+2)%5.
  int hoff = 0;            // stream u16 offset of next half to stage (wraps)
  int ss   = 0;            // its slot (= half index mod 5)
  int s1   = 1, s2 = 2;
  auto stage_half = [&](){ // one 12KB half: 3 stage16 per wave
    const u16* s = stream + hoff + wave*1536 + lane*8;
    u16* d = &wb[ss*HPU + wave*1536];
    stage16(s,        d);
    stage16(s + 512,  d + 512);
    stage16(s + 1024, d + 1024);
    hoff += HPU; if (hoff == STRU) hoff = 0;
    ss = (ss==4) ? 0 : ss+1;
  };
  auto phase_end = [&](){  // counted wait: 3 newest stage-loads stay in flight
    asm volatile("s_waitcnt vmcnt(3) lgkmcnt(0)" ::: "memory");
    __builtin_amdgcn_sched_barrier(0);
    __builtin_amdgcn_s_barrier();
    __builtin_amdgcn_sched_barrier(0);
    s1 = (s1>=3) ? s1-3 : s1+2;
    s2 = (s2>=3) ? s2-3 : s2+2;
  };

  u16x8 bfA[12], bfB[12];

  // prologue: stage halves 0..3; halves 0..2 landed (vmcnt(3)); bfA <- half 0
  // from slot 0; extra lgkm+barrier isolates slot 0 before phase 0 stages
  // half 5 into it.
  stage_half(); stage_half(); stage_half(); stage_half();
  asm volatile("s_waitcnt vmcnt(3)" ::: "memory");
  __builtin_amdgcn_sched_barrier(0);
  __builtin_amdgcn_s_barrier();
  __builtin_amdgcn_sched_barrier(0);
  LOADHALF(bfA, 0);
  lds_fence();
  __builtin_amdgcn_s_barrier();
  __builtin_amdgcn_sched_barrier(0);

#pragma unroll 1
  for (int t=0; t<TT; ++t){
    // ---- x = (state@Ws^T+bs) + gate*(plan@Wp^T+bp) via one padded-K MFMA per tile
    u16x8 a8;
    {
      float4 sv = *(const float4*)&hw[m*HS + 384];   // sst in hn padding
      const float* pp = plan + (size_t)(R0+m)*(TT*3) + t*3;
      float f0=sv.x, f1=sv.y, f2=sv.z, f3=1.f;
      float f4=gt*pp[0], f5=gt*pp[1], f6=gt*pp[2], f7=gt;
      if (hl){ a8[0]=0;a8[1]=0;a8[2]=0;a8[3]=0;a8[4]=0;a8[5]=0;a8[6]=0;a8[7]=0; }
      else { a8[0]=f2b(f0);a8[1]=f2b(f1);a8[2]=f2b(f2);a8[3]=f2b(f3);
             a8[4]=f2b(f4);a8[5]=f2b(f5);a8[6]=f2b(f6);a8[7]=f2b(f7); }
    }
    u16x8 xf[8];
#pragma unroll
    for (int tl=0; tl<4; ++tl){
      f32x16 ax;
#pragma unroll
      for (int r=0;r<16;++r) ax[r]=0.f;
      ax = mfma32(a8, *(const u16x8*)(wxp + tl*512 + lane*8), ax);
      // C-layout -> hn chunk-0 slice (scratch) -> A-frags
#pragma unroll
      for (int r=0;r<16;++r){
        int row = (r&3) + ((r>>2)<<3) + 4*hl;
        hw[row*HS + m] = f2b(ax[r]);
      }
      lds_fence();
      xf[2*tl]   = *(const u16x8*)&hw[m*HS + hl*8];
      xf[2*tl+1] = *(const u16x8*)&hw[m*HS + 16 + hl*8];
      lds_fence();
    }
    // restore chunk-0 slice of old h from hold (CONSTANT indices)
    *(u16x8*)&hw[m*HS + hl*8]      = hold[0];
    *(u16x8*)&hw[m*HS + 16 + hl*8] = hold[1];
    lds_fence();

#pragma unroll 1
    for (int c=0; c<12; ++c){
      f32x16 aR, aZ, aNI, aNH;
      {
        const float4 b4 = *(const float4*)(gb + (size_t)(c*32+m)*4);
#pragma unroll
        for (int r=0;r<16;++r){ aR[r]=b4.x; aZ[r]=b4.y; aNI[r]=b4.z; aNH[r]=b4.w; }
      }
      PH_GI();          // phase c*4+0: gi
      PH_GH(aR);        // phase c*4+1: gh_r
      PH_GH(aZ);        // phase c*4+2: gh_z
      { // phase c*4+3: gh_n + GRU elementwise blend
        LOADHALF(bfB, s1);
#pragma unroll
        for (int kf=0; kf<12; ++kf)
          aNH = mfma32(hold[kf], bfA[kf], aNH);
        LOADHALF(bfA, s2);
        stage_half(); stage_half();
#pragma unroll
        for (int kf=0; kf<12; ++kf)
          aNH = mfma32(hold[12+kf], bfB[kf], aNH);
#pragma unroll
        for (int r=0;r<16;++r){
          int row = (r&3) + ((r>>2)<<3) + 4*hl;
          float rr = sigf(aR[r]);
          float zz = sigf(aZ[r]);
          float nn = tanh_(aNI[r] + rr*aNH[r]);
          int off = row*HS + c*32 + m;
          float ho = b2f(hw[off]);             // old h
          hw[off] = f2b((1.f-zz)*nn + zz*ho);  // new h, in place
        }
        phase_end();
      }
    } // chunks

    // ---- reload hold[] from hn (full new h for this wave's 32 rows)
    lds_fence();
#pragma unroll
    for (int kf=0; kf<24; ++kf)
      hold[kf] = *(const u16x8*)&hw[m*HS + kf*16 + hl*8];

    // ---- decode: d1 = elu(h@Wd1^T + bd1) [2 tiles], then d2 via padded-N MFMA
    f32x16 a0, a1;
#pragma unroll
    for (int r=0;r<16;++r){ a0[r]=bd1v0; a1[r]=bd1v1; }
    PH_GH(a0);          // phase 48: Wd1 tile 0
    { // phase 49: Wd1 tile 1 (+ epilogue); bfA lookahead wraps to next t ph 0
      LOADHALF(bfB, s1);
#pragma unroll
      for (int kf=0; kf<12; ++kf)
        a1 = mfma32(hold[kf], bfA[kf], a1);
      LOADHALF(bfA, s2);
      stage_half(); stage_half();
#pragma unroll
      for (int kf=0; kf<12; ++kf)
        a1 = mfma32(hold[12+kf], bfB[kf], a1);

      // Wd2 frags (short live range, L1-hot)
      u16x8 wd2f0 = *(const u16x8*)(wd2p + 0*512 + lane*8);
      u16x8 wd2f1 = *(const u16x8*)(wd2p + 1*512 + lane*8);
      u16x8 wd2f2 = *(const u16x8*)(wd2p + 2*512 + lane*8);
      u16x8 wd2f3 = *(const u16x8*)(wd2p + 3*512 + lane*8);

      f32x16 ao;
#pragma unroll
      for (int r=0;r<16;++r) ao[r]=0.f;
      // pass 0: d1 units 0..31 (hn chunk-0 slice as scratch)
#pragma unroll
      for (int r=0;r<16;++r){
        int row = (r&3) + ((r>>2)<<3) + 4*hl;
        float e = a0[r]; e = e>0.f ? e : (__expf(e)-1.f);
        hw[row*HS + m] = f2b(e);
      }
      lds_fence();
      {
        u16x8 af0 = *(const u16x8*)&hw[m*HS + hl*8];
        u16x8 af1 = *(const u16x8*)&hw[m*HS + 16 + hl*8];
        ao = mfma32(af0, wd2f0, ao);
        ao = mfma32(af1, wd2f1, ao);
      }
      lds_fence();
      // pass 1: d1 units 32..63
#pragma unroll
      for (int r=0;r<16;++r){
        int row = (r&3) + ((r>>2)<<3) + 4*hl;
        float e = a1[r]; e = e>0.f ? e : (__expf(e)-1.f);
        hw[row*HS + m] = f2b(e);
      }
      lds_fence();
      {
        u16x8 af0 = *(const u16x8*)&hw[m*HS + hl*8];
        u16x8 af1 = *(const u16x8*)&hw[m*HS + 16 + hl*8];
        ao = mfma32(af0, wd2f2, ao);
        ao = mfma32(af1, wd2f3, ao);
      }
      lds_fence();
      // restore chunk-0 slice of NEW h from hold (CONSTANT indices)
      *(u16x8*)&hw[m*HS + hl*8]      = hold[0];
      *(u16x8*)&hw[m*HS + 16 + hl*8] = hold[1];

      // out + state update (C cols 0..2 valid); sst in hn padding
#pragma unroll
      for (int r=0;r<16;++r){
        int row = (r&3) + ((r>>2)<<3) + 4*hl;
        if (m < 3){
          float* q = (float*)&hw[row*HS + 384];
          float ns = q[m] + ao[r] + bd2v;
          out[(size_t)(R0+row)*(TT*3) + t*3 + m] = ns;
          q[m] = ns;
        }
      }
      phase_end();
    }
  } // t
}

// -------------------------------------------------------------- launch ----
extern "C" void kernel_launch(void* const* d_in, const int* in_sizes, int n_in,
                              void* d_out, int out_size, void* d_ws, size_t ws_size,
                              hipStream_t stream)
{
  (void)in_sizes; (void)n_in; (void)out_size; (void)ws_size;
  const float* ih     = (const float*)d_in[0];
  const float* plan   = (const float*)d_in[1];
  const float* gatep  = (const float*)d_in[2];
  const float* istate = (const float*)d_in[3];
  const float* Wp     = (const float*)d_in[4];
  const float* bp     = (const float*)d_in[5];
  const float* Ws     = (const float*)d_in[6];
  const float* bs     = (const float*)d_in[7];
  const float* Wih    = (const float*)d_in[8];
  const float* bih    = (const float*)d_in[9];
  const float* Whh    = (const float*)d_in[10];
  const float* bhh    = (const float*)d_in[11];
  const float* Wd1    = (const float*)d_in[12];
  const float* bd1    = (const float*)d_in[13];
  const float* Wd2    = (const float*)d_in[14];
  const float* bd2    = (const float*)d_in[15];

  // workspace layout (~1.25 MB)
  u16*   wstream = (u16*)d_ws;                         // 614400 u16 = 1228800 B
  u16*   wd2p    = (u16*)((char*)d_ws + 1228800);      //   2048 u16 =    4096 B
  u16*   wxp     = (u16*)((char*)d_ws + 1232896);      //   2048 u16 =    4096 B
  float* gb      = (float*)((char*)d_ws + 1236992);    //   1536 f32 =    6144 B

  prep_kernel<<<1728, 256, 0, stream>>>(Wih, Whh, Wd1, Wd2, bih, bhh, Ws, bs, Wp, bp,
                                        wstream, wd2p, wxp, gb);
  gru_main<<<256, 256, 0, stream>>>(ih, plan, gatep, istate,
                                    wstream, wd2p, wxp, gb, bd1, bd2, (float*)d_out);
}